// Round 11
// baseline (327.975 us; speedup 1.0000x reference)
//
#include <hip/hip_runtime.h>
#include <hip/hip_cooperative_groups.h>
#include <math.h>

namespace cg = cooperative_groups;

#define N_NODES 50000
#define N_EDGES 800000
#define ET (N_EDGES + N_NODES)   // with self-loops
#define NEG 0.2f
#define EPS_BN 1e-5f

#define BSH 8                                   // 256 nodes per bucket
#define NBUCK ((N_NODES + 255) >> BSH)          // 196
#define EPB 4096                                // edges per partition block
#define PB ((ET + EPB - 1) / EPB)               // 208
#define CAST_B 3125                             // 50000*128/8/256
#define PACK_B 64                               // 16384/256
#define GB ((N_NODES + 63) / 64)                // 782 gemm tiles
#define AGG_U 12500                             // aggregate units (4 nodes each)
#define G2B ((N_NODES + 255) / 256)             // 196
#define PREP_U (PB + CAST_B + 2 * PACK_B)       // 3461

typedef __attribute__((ext_vector_type(8))) short short8;
typedef __attribute__((ext_vector_type(4))) float f32x4;

__device__ __forceinline__ float lrelu(float e) { return e > 0.f ? e : NEG * e; }
__device__ __forceinline__ float bflo(unsigned u) { return __uint_as_float(u << 16); }
__device__ __forceinline__ float bfhi(unsigned u) { return __uint_as_float(u & 0xffff0000u); }
__device__ __forceinline__ unsigned f2bf(float f) {           // RNE round to bf16 bits
    unsigned b = __float_as_uint(f);
    return (b + 0x7fffu + ((b >> 16) & 1u)) >> 16;
}

struct GatParams {
    const int* ei;
    const float* x;
    const float *W0, *as0, *ad0, *b0, *g0, *bb0, *rm0, *rv0;
    const float *W1, *as1, *ad1, *b1, *g1, *bb1, *rm1, *rv1;
    const float *W2, *as2, *ad2, *b2;
    float* out;
    unsigned short *xb, *Hb, *Xb, *W0p, *W1p;
    int *offs, *boffs, *bcur, *ssrc, *hists;
    int2* pairs;
    float *asn, *adn, *h2;
};

// =================== shared phase helpers (blk/nblk grid-stride) ===================

// prep unit: u<PB -> per-unit bucket hist; then x cast; then W pack
__device__ __forceinline__ void prep_unit(char* smem, int u, int tid,
        const int* __restrict__ ei, int* __restrict__ hists,
        const float* __restrict__ x, unsigned short* __restrict__ xb,
        const float* __restrict__ W0, unsigned short* __restrict__ W0p,
        const float* __restrict__ W1, unsigned short* __restrict__ W1p) {
    if (u < PB) {
        unsigned* h = (unsigned*)smem;
        __syncthreads();
        for (int i = tid; i < NBUCK; i += 256) h[i] = 0;
        __syncthreads();
        int e0 = u * EPB;
        #pragma unroll
        for (int k = 0; k < EPB / 256; k++) {
            int e = e0 + k * 256 + tid;
            if (e < ET) {
                int d = (e < N_EDGES) ? ei[N_EDGES + e] : (e - N_EDGES);
                atomicAdd(&h[d >> BSH], 1u);
            }
        }
        __syncthreads();
        for (int i = tid; i < NBUCK; i += 256)
            hists[u * NBUCK + i] = (int)h[i];
    } else if (u < PB + CAST_B) {
        int i = (u - PB) * 256 + tid;
        const float4* px = (const float4*)x + (size_t)i * 2;
        float4 a = px[0], c = px[1];
        uint4 o;
        o.x = f2bf(a.x) | (f2bf(a.y) << 16);
        o.y = f2bf(a.z) | (f2bf(a.w) << 16);
        o.z = f2bf(c.x) | (f2bf(c.y) << 16);
        o.w = f2bf(c.z) | (f2bf(c.w) << 16);
        ((uint4*)xb)[i] = o;
    } else {
        int pb = u - PB - CAST_B;
        const float* W = (pb < PACK_B) ? W0 : W1;
        unsigned short* Wp = (pb < PACK_B) ? W0p : W1p;
        int o = (pb & (PACK_B - 1)) * 256 + tid;
        int j = o & 7, lane = (o >> 3) & 63, kc = (o >> 9) & 3, t = o >> 11;
        int k = kc * 32 + ((lane >> 4) << 3) + j;
        int n = t * 16 + (lane & 15);
        Wp[o] = (unsigned short)f2bf(W[k * 128 + n]);
    }
}

// single-block scan: sum per-unit hists -> boffs/bcur; offs[N]=ET
__device__ __forceinline__ void scan_unit(char* smem, int tid,
        const int* __restrict__ hists, int* __restrict__ boffs,
        int* __restrict__ bcur, int* __restrict__ offs) {
    int* s = (int*)smem;
    int v = 0;
    if (tid < NBUCK) {
        const int* hp = hists + tid;
        #pragma unroll 8
        for (int uu = 0; uu < PB; uu++) v += hp[uu * NBUCK];
    }
    s[tid] = v;
    __syncthreads();
    for (int off = 1; off < 256; off <<= 1) {
        int x = (tid >= off) ? s[tid - off] : 0;
        __syncthreads();
        s[tid] += x;
        __syncthreads();
    }
    int excl = s[tid] - v;
    if (tid < NBUCK) { boffs[tid] = excl; bcur[tid] = excl; }
    if (tid == 0) { boffs[NBUCK] = ET; offs[N_NODES] = ET; }
    __syncthreads();
}

__device__ __forceinline__ void partition_unit(char* smem, int u, int tid,
        const int* __restrict__ ei, int* __restrict__ bcur, int2* __restrict__ pairs) {
    unsigned* hist = (unsigned*)smem;
    unsigned* base = hist + NBUCK;
    __syncthreads();
    for (int i = tid; i < NBUCK; i += 256) hist[i] = 0;
    __syncthreads();
    int e0 = u * EPB;
    #pragma unroll
    for (int k = 0; k < EPB / 256; k++) {
        int e = e0 + k * 256 + tid;
        if (e < ET) {
            int d = (e < N_EDGES) ? ei[N_EDGES + e] : (e - N_EDGES);
            atomicAdd(&hist[d >> BSH], 1u);
        }
    }
    __syncthreads();
    for (int i = tid; i < NBUCK; i += 256) {
        unsigned hh = hist[i];
        base[i] = hh ? (unsigned)atomicAdd(&bcur[i], (int)hh) : 0u;
        hist[i] = 0;
    }
    __syncthreads();
    #pragma unroll
    for (int k = 0; k < EPB / 256; k++) {
        int e = e0 + k * 256 + tid;
        if (e < ET) {
            int s, d;
            if (e < N_EDGES) { s = ei[e]; d = ei[N_EDGES + e]; }
            else             { s = d = e - N_EDGES; }
            int b = d >> BSH;
            unsigned lpos = atomicAdd(&hist[b], 1u);
            pairs[base[b] + lpos] = make_int2(s, d);
        }
    }
}

__device__ __forceinline__ void group_unit(char* smem, int u, int tid,
        const int2* __restrict__ pairs, const int* __restrict__ boffs,
        int* __restrict__ offs, int* __restrict__ ssrc) {
    int* cnt = (int*)smem;
    int* pfx = cnt + 256;
    __syncthreads();
    int n0 = u << BSH;
    int base = boffs[u], end = boffs[u + 1];
    cnt[tid] = 0;
    __syncthreads();
    for (int i = base + tid; i < end; i += 256)
        atomicAdd(&cnt[pairs[i].y & 255], 1);
    __syncthreads();
    int v = cnt[tid];
    pfx[tid] = v;
    __syncthreads();
    for (int off = 1; off < 256; off <<= 1) {
        int x = (tid >= off) ? pfx[tid - off] : 0;
        __syncthreads();
        pfx[tid] += x;
        __syncthreads();
    }
    int excl = pfx[tid] - v;
    if (n0 + tid < N_NODES) offs[n0 + tid] = base + excl;
    cnt[tid] = excl;
    __syncthreads();
    for (int i = base + tid; i < end; i += 256) {
        int2 pr = pairs[i];
        int pos = atomicAdd(&cnt[pr.y & 255], 1);
        ssrc[base + pos] = pr.x;
    }
}

__device__ __forceinline__ void gemm_phase(char* smem, int blk, int nblk,
        const unsigned short* __restrict__ Ab, const unsigned short* __restrict__ Wp,
        const float* __restrict__ att_s, const float* __restrict__ att_d,
        unsigned short* __restrict__ Hb, float* __restrict__ asn, float* __restrict__ adn) {
    float* tiles = (float*)smem;                 // 64 x 132
    int tid = threadIdx.x;
    int wv = tid >> 6, lane = tid & 63;
    for (int u = blk; u < GB; u += nblk) {
        int base = u * 64;
        int mrow = base + wv * 16 + (lane & 15);
        if (mrow >= N_NODES) mrow = N_NODES - 1;
        int koff = (lane >> 4) * 8;

        f32x4 acc[8];
        #pragma unroll
        for (int t = 0; t < 8; t++) acc[t] = (f32x4){0.f, 0.f, 0.f, 0.f};
        #pragma unroll
        for (int kc = 0; kc < 4; kc++) {
            short8 a = *(const short8*)(Ab + (size_t)mrow * 128 + kc * 32 + koff);
            #pragma unroll
            for (int t = 0; t < 8; t++) {
                short8 b = *(const short8*)(Wp + (((t * 4 + kc) * 64 + lane) << 3));
                acc[t] = __builtin_amdgcn_mfma_f32_16x16x32_bf16(a, b, acc[t], 0, 0, 0);
            }
        }
        __syncthreads();
        int rbase = wv * 16 + (lane >> 4) * 4;
        int col = lane & 15;
        #pragma unroll
        for (int t = 0; t < 8; t++)
            #pragma unroll
            for (int r = 0; r < 4; r++)
                tiles[(rbase + r) * 132 + t * 16 + col] = acc[t][r];
        __syncthreads();

        #pragma unroll
        for (int it = 0; it < 4; it++) {
            int uu = tid + it * 256;
            int rl = uu >> 4, cg4 = uu & 15;
            int row = base + rl;
            if (row < N_NODES) {
                const float* pt = tiles + rl * 132 + cg4 * 8;
                float4 v0 = *(const float4*)(pt);
                float4 v1 = *(const float4*)(pt + 4);
                uint4 o;
                o.x = f2bf(v0.x) | (f2bf(v0.y) << 16);
                o.y = f2bf(v0.z) | (f2bf(v0.w) << 16);
                o.z = f2bf(v1.x) | (f2bf(v1.y) << 16);
                o.w = f2bf(v1.z) | (f2bf(v1.w) << 16);
                *(uint4*)(Hb + (size_t)row * 128 + cg4 * 8) = o;
            }
        }
        {
            int rl = tid >> 2, hd = tid & 3;
            int row = base + rl;
            if (row < N_NODES) {
                const float* hrow = tiles + rl * 132 + hd * 32;
                const float* as = att_s + hd * 32;
                const float* ad = att_d + hd * 32;
                float ps = 0.f, pd = 0.f;
                #pragma unroll
                for (int i = 0; i < 8; i++) {
                    float4 hv = *(const float4*)(hrow + i * 4);
                    float4 sv = *(const float4*)(as + i * 4);
                    float4 dv = *(const float4*)(ad + i * 4);
                    ps += hv.x * sv.x + hv.y * sv.y + hv.z * sv.z + hv.w * sv.w;
                    pd += hv.x * dv.x + hv.y * dv.y + hv.z * dv.z + hv.w * dv.w;
                }
                asn[row * 4 + hd] = ps;
                adn[row * 4 + hd] = pd;
            }
        }
        __syncthreads();
    }
}

__device__ __forceinline__ void aggregate_phase(char* smem, int blk, int nblk,
        const unsigned short* __restrict__ hb, const float* __restrict__ asn,
        const float* __restrict__ adn, const int* __restrict__ offs,
        const int* __restrict__ ssrc, const float* __restrict__ bias,
        const float* __restrict__ gamma, const float* __restrict__ beta,
        const float* __restrict__ rmean, const float* __restrict__ rvar,
        unsigned short* __restrict__ outb) {
    int2* sP = (int2*)smem;                      // [4 waves][4 heads][72]
    int tid = threadIdx.x;
    int wv = tid >> 6, lane = tid & 63;
    int half = lane >> 5, cl = lane & 31, hsel = cl >> 3;
    const char* hbase = (const char*)hb + cl * 8;
    int2* st0 = sP + (wv * 4 + 0) * 72;
    int2* st1 = sP + (wv * 4 + 1) * 72;
    int2* st2 = sP + (wv * 4 + 2) * 72;
    int2* st3 = sP + (wv * 4 + 3) * 72;
    const int2* pp = sP + (wv * 4 + hsel) * 72;

    for (int u = blk; u < AGG_U; u += nblk) {
        int node = u * 4 + wv;
        int beg = offs[node], deg = offs[node + 1] - beg;
        float4 ad4 = *(const float4*)(adn + node * 4);
        float a0 = 0.f, a1 = 0.f, a2 = 0.f, a3 = 0.f, denl = 0.f;

        for (int base0 = 0; base0 < deg; base0 += 64) {
            int j = base0 + lane;
            int soff = 0;
            float4 w4v = make_float4(0.f, 0.f, 0.f, 0.f);
            if (j < deg) {
                int s = ssrc[beg + j];
                soff = s << 8;                   // byte offset into 256 B rows
                float4 a = *(const float4*)(asn + s * 4);
                w4v.x = __expf(lrelu(a.x + ad4.x));
                w4v.y = __expf(lrelu(a.y + ad4.y));
                w4v.z = __expf(lrelu(a.z + ad4.z));
                w4v.w = __expf(lrelu(a.w + ad4.w));
            }
            st0[lane] = make_int2(soff, __float_as_int(w4v.x));
            st1[lane] = make_int2(soff, __float_as_int(w4v.y));
            st2[lane] = make_int2(soff, __float_as_int(w4v.z));
            st3[lane] = make_int2(soff, __float_as_int(w4v.w));
            int cnt = deg - base0; if (cnt > 64) cnt = 64;
            int bound = (cnt + 15) & ~15;
            for (int i = 0; i < bound; i += 16) {
                int2 p0 = pp[i + 0 + half],  p1 = pp[i + 2 + half];
                int2 p2 = pp[i + 4 + half],  p3 = pp[i + 6 + half];
                int2 p4 = pp[i + 8 + half],  p5 = pp[i + 10 + half];
                int2 p6 = pp[i + 12 + half], p7 = pp[i + 14 + half];
                uint2 u0 = *(const uint2*)(hbase + (unsigned)p0.x);
                uint2 u1 = *(const uint2*)(hbase + (unsigned)p1.x);
                uint2 u2 = *(const uint2*)(hbase + (unsigned)p2.x);
                uint2 u3 = *(const uint2*)(hbase + (unsigned)p3.x);
                uint2 u4 = *(const uint2*)(hbase + (unsigned)p4.x);
                uint2 u5 = *(const uint2*)(hbase + (unsigned)p5.x);
                uint2 u6 = *(const uint2*)(hbase + (unsigned)p6.x);
                uint2 u7 = *(const uint2*)(hbase + (unsigned)p7.x);
                float w0 = __int_as_float(p0.y), w1 = __int_as_float(p1.y);
                float w2 = __int_as_float(p2.y), w3 = __int_as_float(p3.y);
                float w4 = __int_as_float(p4.y), w5 = __int_as_float(p5.y);
                float w6 = __int_as_float(p6.y), w7 = __int_as_float(p7.y);
                denl += w0 + w1 + w2 + w3 + w4 + w5 + w6 + w7;
                a0 += w0 * bflo(u0.x); a1 += w0 * bfhi(u0.x); a2 += w0 * bflo(u0.y); a3 += w0 * bfhi(u0.y);
                a0 += w1 * bflo(u1.x); a1 += w1 * bfhi(u1.x); a2 += w1 * bflo(u1.y); a3 += w1 * bfhi(u1.y);
                a0 += w2 * bflo(u2.x); a1 += w2 * bfhi(u2.x); a2 += w2 * bflo(u2.y); a3 += w2 * bfhi(u2.y);
                a0 += w3 * bflo(u3.x); a1 += w3 * bfhi(u3.x); a2 += w3 * bflo(u3.y); a3 += w3 * bfhi(u3.y);
                a0 += w4 * bflo(u4.x); a1 += w4 * bfhi(u4.x); a2 += w4 * bflo(u4.y); a3 += w4 * bfhi(u4.y);
                a0 += w5 * bflo(u5.x); a1 += w5 * bfhi(u5.x); a2 += w5 * bflo(u5.y); a3 += w5 * bfhi(u5.y);
                a0 += w6 * bflo(u6.x); a1 += w6 * bfhi(u6.x); a2 += w6 * bflo(u6.y); a3 += w6 * bfhi(u6.y);
                a0 += w7 * bflo(u7.x); a1 += w7 * bfhi(u7.x); a2 += w7 * bflo(u7.y); a3 += w7 * bfhi(u7.y);
            }
        }
        a0 += __shfl_xor(a0, 32); a1 += __shfl_xor(a1, 32);
        a2 += __shfl_xor(a2, 32); a3 += __shfl_xor(a3, 32);
        denl += __shfl_xor(denl, 32);
        if (half == 0) {
            float inv = 1.f / (denl + 1e-16f);
            int c0 = cl * 4;
            float4 bi = *(const float4*)(bias + c0);
            float4 gm = *(const float4*)(gamma + c0);
            float4 bt = *(const float4*)(beta + c0);
            float4 rm = *(const float4*)(rmean + c0);
            float4 rv = *(const float4*)(rvar + c0);
            float o0 = a0 * inv + bi.x, o1 = a1 * inv + bi.y;
            float o2 = a2 * inv + bi.z, o3 = a3 * inv + bi.w;
            o0 = (o0 - rm.x) * rsqrtf(rv.x + EPS_BN) * gm.x + bt.x;
            o1 = (o1 - rm.y) * rsqrtf(rv.y + EPS_BN) * gm.y + bt.y;
            o2 = (o2 - rm.z) * rsqrtf(rv.z + EPS_BN) * gm.z + bt.z;
            o3 = (o3 - rm.w) * rsqrtf(rv.w + EPS_BN) * gm.w + bt.w;
            o0 = (o0 > 0.f) ? o0 : expm1f(o0);
            o1 = (o1 > 0.f) ? o1 : expm1f(o1);
            o2 = (o2 > 0.f) ? o2 : expm1f(o2);
            o3 = (o3 > 0.f) ? o3 : expm1f(o3);
            uint2 ob;
            ob.x = f2bf(o0) | (f2bf(o1) << 16);
            ob.y = f2bf(o2) | (f2bf(o3) << 16);
            *(uint2*)(outb + (size_t)node * 128 + c0) = ob;
        }
    }
}

__device__ __forceinline__ void gemm2_unit(char* smem, int u, int tid,
        const unsigned short* __restrict__ xb, const float* __restrict__ W2,
        const float* __restrict__ as2, const float* __restrict__ ad2,
        float* __restrict__ h2, float* __restrict__ asn, float* __restrict__ adn,
        bool loadW) {
    float* sW = (float*)smem;
    float* sas = sW + 1024;
    float* sad = sas + 8;
    if (loadW) {
        for (int i = tid; i < 1024; i += 256) sW[i] = W2[i];
        if (tid < 8) { sas[tid] = as2[tid]; sad[tid] = ad2[tid]; }
        __syncthreads();
    }
    int node = u * 256 + tid;
    if (node >= N_NODES) return;
    const uint4* xr = (const uint4*)(xb + (size_t)node * 128);
    float acc[8];
    #pragma unroll
    for (int c = 0; c < 8; c++) acc[c] = 0.f;
    for (int k8 = 0; k8 < 16; k8++) {
        uint4 uu = xr[k8];
        float f[8] = { bflo(uu.x), bfhi(uu.x), bflo(uu.y), bfhi(uu.y),
                       bflo(uu.z), bfhi(uu.z), bflo(uu.w), bfhi(uu.w) };
        int kb = k8 * 8;
        #pragma unroll
        for (int q = 0; q < 8; q++)
            #pragma unroll
            for (int c = 0; c < 8; c++)
                acc[c] += f[q] * sW[(kb + q) * 8 + c];
    }
    float ps = 0.f, pd = 0.f;
    #pragma unroll
    for (int c = 0; c < 8; c++) {
        h2[(size_t)node * 8 + c] = acc[c];
        ps += acc[c] * sas[c];
        pd += acc[c] * sad[c];
    }
    asn[node] = ps;
    adn[node] = pd;
}

__device__ __forceinline__ void agg2_unit(char* smem, int u, int tid,
        const float* __restrict__ h2, const float* __restrict__ asn,
        const float* __restrict__ adn, const int* __restrict__ offs,
        const int* __restrict__ ssrc, const float* __restrict__ b2,
        float* __restrict__ out) {
    int2* sP = (int2*)smem;    // [4][64]
    int wv = tid >> 6, lane = tid & 63;
    int g = lane >> 3, c = lane & 7;
    int node = u * 4 + wv;
    int beg = offs[node], end = offs[node + 1];
    int deg = end - beg;
    float adv = adn[node];
    float den = 0.f, acc = 0.f;
    int2* ws = sP + wv * 64;
    for (int base = 0; base < deg; base += 64) {
        int j = base + lane;
        int s = 0; float w = 0.f;
        if (j < deg) {
            s = ssrc[beg + j];
            w = __expf(lrelu(asn[s] + adv));
            den += w;
        }
        ws[lane] = make_int2(s, __float_as_int(w));
        int cnt = deg - base; if (cnt > 64) cnt = 64;
        int nIt = (cnt + 15) >> 4;
        for (int i = 0; i < nIt; i++) {
            int e = i * 16 + g;
            int2 p0 = ws[e];
            int2 p1 = ws[e + 8];
            acc += __int_as_float(p0.y) * h2[(((unsigned)p0.x) << 3) + c];
            acc += __int_as_float(p1.y) * h2[(((unsigned)p1.x) << 3) + c];
        }
    }
    acc += __shfl_xor(acc, 8); acc += __shfl_xor(acc, 16); acc += __shfl_xor(acc, 32);
    #pragma unroll
    for (int off = 32; off; off >>= 1) den += __shfl_xor(den, off);
    float o = acc / (den + 1e-16f) + b2[c];
    float mx = o;
    mx = fmaxf(mx, __shfl_xor(mx, 1));
    mx = fmaxf(mx, __shfl_xor(mx, 2));
    mx = fmaxf(mx, __shfl_xor(mx, 4));
    float ex = __expf(o - mx);
    float sm = ex;
    sm += __shfl_xor(sm, 1); sm += __shfl_xor(sm, 2); sm += __shfl_xor(sm, 4);
    if (g == 0) out[(size_t)node * 8 + c] = o - mx - logf(sm);
}

// =================== cooperative mega-kernel ===================

__global__ __launch_bounds__(256, 3) void gat_mega(GatParams p) {
    cg::grid_group grid = cg::this_grid();
    __shared__ __align__(16) char smem[64 * 132 * 4];
    const int blk = blockIdx.x, nblk = gridDim.x, tid = threadIdx.x;

    for (int u = blk; u < PREP_U; u += nblk)
        prep_unit(smem, u, tid, p.ei, p.hists, p.x, p.xb, p.W0, p.W0p, p.W1, p.W1p);
    grid.sync();

    if (blk == 0) scan_unit(smem, tid, p.hists, p.boffs, p.bcur, p.offs);
    gemm_phase(smem, blk, nblk, p.xb, p.W0p, p.as0, p.ad0, p.Hb, p.asn, p.adn);
    grid.sync();

    for (int u = blk; u < PB; u += nblk)
        partition_unit(smem, u, tid, p.ei, p.bcur, p.pairs);
    grid.sync();

    for (int u = blk; u < NBUCK; u += nblk)
        group_unit(smem, u, tid, p.pairs, p.boffs, p.offs, p.ssrc);
    grid.sync();

    aggregate_phase(smem, blk, nblk, p.Hb, p.asn, p.adn, p.offs, p.ssrc,
                    p.b0, p.g0, p.bb0, p.rm0, p.rv0, p.Xb);
    grid.sync();

    gemm_phase(smem, blk, nblk, p.Xb, p.W1p, p.as1, p.ad1, p.Hb, p.asn, p.adn);
    grid.sync();

    aggregate_phase(smem, blk, nblk, p.Hb, p.asn, p.adn, p.offs, p.ssrc,
                    p.b1, p.g1, p.bb1, p.rm1, p.rv1, p.Xb);
    grid.sync();

    {   // gemm2: load W once per block, then grid-stride
        float* sW = (float*)smem;
        float* sas = sW + 1024;
        float* sad = sas + 8;
        __syncthreads();
        for (int i = tid; i < 1024; i += 256) sW[i] = p.W2[i];
        if (tid < 8) { sas[tid] = p.as2[tid]; sad[tid] = p.ad2[tid]; }
        __syncthreads();
        for (int u = blk; u < G2B; u += nblk)
            gemm2_unit(smem, u, tid, p.Xb, p.W2, p.as2, p.ad2, p.h2, p.asn, p.adn, false);
    }
    grid.sync();

    for (int u = blk; u < AGG_U; u += nblk) {
        __syncthreads();
        agg2_unit(smem, u, tid, p.h2, p.asn, p.adn, p.offs, p.ssrc, p.b2, p.out);
    }
}

// =================== standalone fallback kernels ===================

__global__ __launch_bounds__(256) void k_prep(GatParams p) {
    __shared__ __align__(16) char smem[1024];
    prep_unit(smem, blockIdx.x, threadIdx.x, p.ei, p.hists, p.x, p.xb,
              p.W0, p.W0p, p.W1, p.W1p);
}
__global__ __launch_bounds__(256) void k_scan(GatParams p) {
    __shared__ __align__(16) char smem[1024];
    scan_unit(smem, threadIdx.x, p.hists, p.boffs, p.bcur, p.offs);
}
__global__ __launch_bounds__(256) void k_partition(GatParams p) {
    __shared__ __align__(16) char smem[2048];
    partition_unit(smem, blockIdx.x, threadIdx.x, p.ei, p.bcur, p.pairs);
}
__global__ __launch_bounds__(256) void k_group(GatParams p) {
    __shared__ __align__(16) char smem[2048];
    group_unit(smem, blockIdx.x, threadIdx.x, p.pairs, p.boffs, p.offs, p.ssrc);
}
__global__ __launch_bounds__(256) void k_gemm(GatParams p, int layer) {
    __shared__ __align__(16) char smem[64 * 132 * 4];
    if (layer == 0)
        gemm_phase(smem, blockIdx.x, gridDim.x, p.xb, p.W0p, p.as0, p.ad0,
                   p.Hb, p.asn, p.adn);
    else
        gemm_phase(smem, blockIdx.x, gridDim.x, p.Xb, p.W1p, p.as1, p.ad1,
                   p.Hb, p.asn, p.adn);
}
__global__ __launch_bounds__(256) void k_agg(GatParams p, int layer) {
    __shared__ __align__(16) char smem[4 * 4 * 72 * 8];
    if (layer == 0)
        aggregate_phase(smem, blockIdx.x, gridDim.x, p.Hb, p.asn, p.adn, p.offs,
                        p.ssrc, p.b0, p.g0, p.bb0, p.rm0, p.rv0, p.Xb);
    else
        aggregate_phase(smem, blockIdx.x, gridDim.x, p.Hb, p.asn, p.adn, p.offs,
                        p.ssrc, p.b1, p.g1, p.bb1, p.rm1, p.rv1, p.Xb);
}
__global__ __launch_bounds__(256) void k_gemm2(GatParams p) {
    __shared__ __align__(16) char smem[1040 * 4];
    gemm2_unit(smem, blockIdx.x, threadIdx.x, p.Xb, p.W2, p.as2, p.ad2,
               p.h2, p.asn, p.adn, true);
}
__global__ __launch_bounds__(256) void k_agg2(GatParams p) {
    __shared__ __align__(16) char smem[4 * 64 * 8];
    agg2_unit(smem, blockIdx.x, threadIdx.x, p.h2, p.asn, p.adn, p.offs,
              p.ssrc, p.b2, p.out);
}

// =================== launch ===================

extern "C" void kernel_launch(void* const* d_in, const int* in_sizes, int n_in,
                              void* d_out, int out_size, void* d_ws, size_t ws_size,
                              hipStream_t stream) {
    GatParams prm;
    prm.ei  = (const int*)d_in[1];
    prm.x   = (const float*)d_in[0];
    prm.W0  = (const float*)d_in[2];
    prm.as0 = (const float*)d_in[3];  prm.ad0 = (const float*)d_in[4];
    prm.b0  = (const float*)d_in[5];  prm.g0  = (const float*)d_in[6];
    prm.bb0 = (const float*)d_in[7];  prm.rm0 = (const float*)d_in[8];
    prm.rv0 = (const float*)d_in[9];
    prm.W1  = (const float*)d_in[10];
    prm.as1 = (const float*)d_in[11]; prm.ad1 = (const float*)d_in[12];
    prm.b1  = (const float*)d_in[13]; prm.g1  = (const float*)d_in[14];
    prm.bb1 = (const float*)d_in[15]; prm.rm1 = (const float*)d_in[16];
    prm.rv1 = (const float*)d_in[17];
    prm.W2  = (const float*)d_in[18];
    prm.as2 = (const float*)d_in[19]; prm.ad2 = (const float*)d_in[20];
    prm.b2  = (const float*)d_in[21];
    prm.out = (float*)d_out;

    char* w = (char*)d_ws;
    size_t off = 0;
    auto carve = [&](size_t bytes) {
        void* p = w + off;
        off += (bytes + 255) & ~(size_t)255;
        return p;
    };
    prm.xb    = (unsigned short*)carve((size_t)N_NODES * 128 * 2);
    prm.Hb    = (unsigned short*)carve((size_t)N_NODES * 128 * 2);
    prm.Xb    = (unsigned short*)carve((size_t)N_NODES * 128 * 2);
    prm.W0p   = (unsigned short*)carve(16384 * 2);
    prm.W1p   = (unsigned short*)carve(16384 * 2);
    prm.offs  = (int*)carve((size_t)(N_NODES + 1) * 4);
    prm.boffs = (int*)carve((size_t)(NBUCK + 1) * 4);
    prm.bcur  = (int*)carve((size_t)NBUCK * 4);
    prm.ssrc  = (int*)carve((size_t)ET * 4);
    prm.hists = (int*)carve((size_t)PB * NBUCK * 4);
    prm.pairs = (int2*)carve((size_t)ET * 8);
    prm.asn   = (float*)carve((size_t)N_NODES * 4 * 4);
    prm.adn   = (float*)carve((size_t)N_NODES * 4 * 4);
    prm.h2    = (float*)carve((size_t)N_NODES * 8 * 4);
    (void)ws_size; (void)in_sizes; (void)n_in; (void)out_size;

    // Try cooperative single-kernel path; fall back to multi-kernel pipeline.
    bool coop_done = false;
    int mb = 0;
    if (hipOccupancyMaxActiveBlocksPerMultiprocessor(
            &mb, (const void*)gat_mega, 256, 0) == hipSuccess && mb >= 2) {
        int nb = (mb >= 3) ? 768 : 512;          // <= mb * 256 CUs co-resident
        void* args[] = { (void*)&prm };
        if (hipLaunchCooperativeKernel((const void*)gat_mega, dim3(nb), dim3(256),
                                       args, 0, stream) == hipSuccess)
            coop_done = true;
    }
    if (!coop_done) {
        k_prep<<<PREP_U, 256, 0, stream>>>(prm);
        k_scan<<<1, 256, 0, stream>>>(prm);
        k_partition<<<PB, 256, 0, stream>>>(prm);
        k_group<<<NBUCK, 256, 0, stream>>>(prm);
        k_gemm<<<GB, 256, 0, stream>>>(prm, 0);
        k_agg<<<AGG_U, 256, 0, stream>>>(prm, 0);
        k_gemm<<<GB, 256, 0, stream>>>(prm, 1);
        k_agg<<<AGG_U, 256, 0, stream>>>(prm, 1);
        k_gemm2<<<G2B, 256, 0, stream>>>(prm);
        k_agg2<<<AGG_U, 256, 0, stream>>>(prm);
    }
}

// Round 12
// 291.527 us; speedup vs baseline: 1.1250x; 1.1250x over previous
//
#include <hip/hip_runtime.h>
#include <math.h>

#define N_NODES 50000
#define N_EDGES 800000
#define ET (N_EDGES + N_NODES)   // with self-loops
#define NEG 0.2f
#define EPS_BN 1e-5f

#define BSH 8                                   // 256 nodes per bucket
#define NBUCK ((N_NODES + 255) >> BSH)          // 196
#define EPB 4096                                // edges per partition block
#define PB ((ET + EPB - 1) / EPB)               // 208
#define CAST_B 3125                             // 50000*128/8/256
#define PACK_B 64                               // 16384/256
#define GB ((N_NODES + 63) / 64)                // 782 gemm tiles
#define AGG_U 12500                             // aggregate units (4 nodes each)
#define G2B ((N_NODES + 255) / 256)             // 196
#define PREP_U (PB + CAST_B + 2 * PACK_B)       // 3461

typedef __attribute__((ext_vector_type(8))) short short8;
typedef __attribute__((ext_vector_type(4))) float f32x4;

__device__ __forceinline__ float lrelu(float e) { return e > 0.f ? e : NEG * e; }
__device__ __forceinline__ float bflo(unsigned u) { return __uint_as_float(u << 16); }
__device__ __forceinline__ float bfhi(unsigned u) { return __uint_as_float(u & 0xffff0000u); }
__device__ __forceinline__ unsigned f2bf(float f) {           // RNE round to bf16 bits
    unsigned b = __float_as_uint(f);
    return (b + 0x7fffu + ((b >> 16) & 1u)) >> 16;
}

struct GatParams {
    const int* ei;
    const float* x;
    const float *W0, *as0, *ad0, *b0, *g0, *bb0, *rm0, *rv0;
    const float *W1, *as1, *ad1, *b1, *g1, *bb1, *rm1, *rv1;
    const float *W2, *as2, *ad2, *b2;
    float* out;
    unsigned short *xb, *Hb, *Xb, *W0p, *W1p;
    int *offs, *boffs, *bcur, *ssrc, *hists;
    int2* pairs;
    float *asn, *adn, *h2;
};

// =================== graph prep + input prep ===================

// prep unit: u<PB -> per-unit bucket hist; then x cast; then W pack
__global__ __launch_bounds__(256) void k_prep(GatParams p) {
    __shared__ unsigned h[NBUCK];
    int u = blockIdx.x, tid = threadIdx.x;
    if (u < PB) {
        for (int i = tid; i < NBUCK; i += 256) h[i] = 0;
        __syncthreads();
        int e0 = u * EPB;
        #pragma unroll
        for (int k = 0; k < EPB / 256; k++) {
            int e = e0 + k * 256 + tid;
            if (e < ET) {
                int d = (e < N_EDGES) ? p.ei[N_EDGES + e] : (e - N_EDGES);
                atomicAdd(&h[d >> BSH], 1u);
            }
        }
        __syncthreads();
        for (int i = tid; i < NBUCK; i += 256)
            p.hists[u * NBUCK + i] = (int)h[i];
    } else if (u < PB + CAST_B) {
        int i = (u - PB) * 256 + tid;
        const float4* px = (const float4*)p.x + (size_t)i * 2;
        float4 a = px[0], c = px[1];
        uint4 o;
        o.x = f2bf(a.x) | (f2bf(a.y) << 16);
        o.y = f2bf(a.z) | (f2bf(a.w) << 16);
        o.z = f2bf(c.x) | (f2bf(c.y) << 16);
        o.w = f2bf(c.z) | (f2bf(c.w) << 16);
        ((uint4*)p.xb)[i] = o;
    } else {
        int pb = u - PB - CAST_B;
        const float* W = (pb < PACK_B) ? p.W0 : p.W1;
        unsigned short* Wp = (pb < PACK_B) ? p.W0p : p.W1p;
        int o = (pb & (PACK_B - 1)) * 256 + tid;
        int j = o & 7, lane = (o >> 3) & 63, kc = (o >> 9) & 3, t = o >> 11;
        int k = kc * 32 + ((lane >> 4) << 3) + j;
        int n = t * 16 + (lane & 15);
        Wp[o] = (unsigned short)f2bf(W[k * 128 + n]);
    }
}

// single block: sum per-unit hists -> exclusive scan -> boffs/bcur; offs[N]=ET
__global__ __launch_bounds__(256) void k_scan(GatParams p) {
    __shared__ int s[256];
    int tid = threadIdx.x;
    int v = 0;
    if (tid < NBUCK) {
        const int* hp = p.hists + tid;
        #pragma unroll 8
        for (int uu = 0; uu < PB; uu++) v += hp[uu * NBUCK];
    }
    s[tid] = v;
    __syncthreads();
    for (int off = 1; off < 256; off <<= 1) {
        int x = (tid >= off) ? s[tid - off] : 0;
        __syncthreads();
        s[tid] += x;
        __syncthreads();
    }
    int excl = s[tid] - v;
    if (tid < NBUCK) { p.boffs[tid] = excl; p.bcur[tid] = excl; }
    if (tid == 0) { p.boffs[NBUCK] = ET; p.offs[N_NODES] = ET; }
}

__global__ __launch_bounds__(256) void k_partition(GatParams p) {
    __shared__ unsigned hist[NBUCK];
    __shared__ unsigned base[NBUCK];
    int tid = threadIdx.x;
    int e0 = blockIdx.x * EPB;
    for (int i = tid; i < NBUCK; i += 256) hist[i] = 0;
    __syncthreads();
    #pragma unroll
    for (int k = 0; k < EPB / 256; k++) {
        int e = e0 + k * 256 + tid;
        if (e < ET) {
            int d = (e < N_EDGES) ? p.ei[N_EDGES + e] : (e - N_EDGES);
            atomicAdd(&hist[d >> BSH], 1u);
        }
    }
    __syncthreads();
    for (int i = tid; i < NBUCK; i += 256) {
        unsigned hh = hist[i];
        base[i] = hh ? (unsigned)atomicAdd(&p.bcur[i], (int)hh) : 0u;
        hist[i] = 0;
    }
    __syncthreads();
    #pragma unroll
    for (int k = 0; k < EPB / 256; k++) {
        int e = e0 + k * 256 + tid;
        if (e < ET) {
            int s, d;
            if (e < N_EDGES) { s = p.ei[e]; d = p.ei[N_EDGES + e]; }
            else             { s = d = e - N_EDGES; }
            int b = d >> BSH;
            unsigned lpos = atomicAdd(&hist[b], 1u);
            p.pairs[base[b] + lpos] = make_int2(s, d);
        }
    }
}

__global__ __launch_bounds__(256) void k_group(GatParams p) {
    __shared__ int cnt[256];
    __shared__ int pfx[256];
    int u = blockIdx.x, tid = threadIdx.x;
    int n0 = u << BSH;
    int base = p.boffs[u], end = p.boffs[u + 1];
    cnt[tid] = 0;
    __syncthreads();
    for (int i = base + tid; i < end; i += 256)
        atomicAdd(&cnt[p.pairs[i].y & 255], 1);
    __syncthreads();
    int v = cnt[tid];
    pfx[tid] = v;
    __syncthreads();
    for (int off = 1; off < 256; off <<= 1) {
        int x = (tid >= off) ? pfx[tid - off] : 0;
        __syncthreads();
        pfx[tid] += x;
        __syncthreads();
    }
    int excl = pfx[tid] - v;
    if (n0 + tid < N_NODES) p.offs[n0 + tid] = base + excl;
    cnt[tid] = excl;
    __syncthreads();
    for (int i = base + tid; i < end; i += 256) {
        int2 pr = p.pairs[i];
        int pos = atomicAdd(&cnt[pr.y & 255], 1);
        p.ssrc[base + pos] = pr.x;
    }
}

// =================== MFMA GEMM + bf16 h-store + attn coeffs ===================

__global__ __launch_bounds__(256) void k_gemm(GatParams p, int layer) {
    __shared__ float tiles[64 * 132];
    const unsigned short* Ab = (layer == 0) ? p.xb : p.Xb;
    const unsigned short* Wp = (layer == 0) ? p.W0p : p.W1p;
    const float* att_s = (layer == 0) ? p.as0 : p.as1;
    const float* att_d = (layer == 0) ? p.ad0 : p.ad1;
    int tid = threadIdx.x;
    int wv = tid >> 6, lane = tid & 63;
    int base = blockIdx.x * 64;
    int mrow = base + wv * 16 + (lane & 15);
    if (mrow >= N_NODES) mrow = N_NODES - 1;
    int koff = (lane >> 4) * 8;

    f32x4 acc[8];
    #pragma unroll
    for (int t = 0; t < 8; t++) acc[t] = (f32x4){0.f, 0.f, 0.f, 0.f};
    #pragma unroll
    for (int kc = 0; kc < 4; kc++) {
        short8 a = *(const short8*)(Ab + (size_t)mrow * 128 + kc * 32 + koff);
        #pragma unroll
        for (int t = 0; t < 8; t++) {
            short8 b = *(const short8*)(Wp + (((t * 4 + kc) * 64 + lane) << 3));
            acc[t] = __builtin_amdgcn_mfma_f32_16x16x32_bf16(a, b, acc[t], 0, 0, 0);
        }
    }
    int rbase = wv * 16 + (lane >> 4) * 4;
    int col = lane & 15;
    #pragma unroll
    for (int t = 0; t < 8; t++)
        #pragma unroll
        for (int r = 0; r < 4; r++)
            tiles[(rbase + r) * 132 + t * 16 + col] = acc[t][r];
    __syncthreads();

    #pragma unroll
    for (int it = 0; it < 4; it++) {
        int uu = tid + it * 256;
        int rl = uu >> 4, cg4 = uu & 15;
        int row = base + rl;
        if (row < N_NODES) {
            const float* pt = tiles + rl * 132 + cg4 * 8;
            float4 v0 = *(const float4*)(pt);
            float4 v1 = *(const float4*)(pt + 4);
            uint4 o;
            o.x = f2bf(v0.x) | (f2bf(v0.y) << 16);
            o.y = f2bf(v0.z) | (f2bf(v0.w) << 16);
            o.z = f2bf(v1.x) | (f2bf(v1.y) << 16);
            o.w = f2bf(v1.z) | (f2bf(v1.w) << 16);
            *(uint4*)(p.Hb + (size_t)row * 128 + cg4 * 8) = o;
        }
    }
    {
        int rl = tid >> 2, hd = tid & 3;
        int row = base + rl;
        if (row < N_NODES) {
            const float* hrow = tiles + rl * 132 + hd * 32;
            const float* as = att_s + hd * 32;
            const float* ad = att_d + hd * 32;
            float ps = 0.f, pd = 0.f;
            #pragma unroll
            for (int i = 0; i < 8; i++) {
                float4 hv = *(const float4*)(hrow + i * 4);
                float4 sv = *(const float4*)(as + i * 4);
                float4 dv = *(const float4*)(ad + i * 4);
                ps += hv.x * sv.x + hv.y * sv.y + hv.z * sv.z + hv.w * sv.w;
                pd += hv.x * dv.x + hv.y * dv.y + hv.z * dv.z + hv.w * dv.w;
            }
            p.asn[row * 4 + hd] = ps;
            p.adn[row * 4 + hd] = pd;
        }
    }
}

// =================== aggregation + bias + BN + ELU ===================
// Phase C: lane owns 4 channels (uint2); half-wave 0 even edges, half-wave 1 odd.
// 16-edge unrolled main loop + 4-edge-granularity tail (deg 17 -> 20 slots, not 32).
// Tail slot index <= 63 always (sweep writes all 64 slots; pads have w=0).

__global__ __launch_bounds__(256) void k_agg(GatParams p, int layer) {
    __shared__ int2 sP[4 * 4 * 72];              // [wave][head][72]
    const float* bias  = (layer == 0) ? p.b0  : p.b1;
    const float* gamma = (layer == 0) ? p.g0  : p.g1;
    const float* beta  = (layer == 0) ? p.bb0 : p.bb1;
    const float* rmean = (layer == 0) ? p.rm0 : p.rm1;
    const float* rvar  = (layer == 0) ? p.rv0 : p.rv1;
    int tid = threadIdx.x;
    int wv = tid >> 6, lane = tid & 63;
    int half = lane >> 5, cl = lane & 31, hsel = cl >> 3;
    const char* hbase = (const char*)p.Hb + cl * 8;
    int2* st0 = sP + (wv * 4 + 0) * 72;
    int2* st1 = sP + (wv * 4 + 1) * 72;
    int2* st2 = sP + (wv * 4 + 2) * 72;
    int2* st3 = sP + (wv * 4 + 3) * 72;
    const int2* pp = sP + (wv * 4 + hsel) * 72;

    int node = blockIdx.x * 4 + wv;
    int beg = p.offs[node], deg = p.offs[node + 1] - beg;
    float4 ad4 = *(const float4*)(p.adn + node * 4);
    float a0 = 0.f, a1 = 0.f, a2 = 0.f, a3 = 0.f, denl = 0.f;

    for (int base0 = 0; base0 < deg; base0 += 64) {
        int j = base0 + lane;
        int soff = 0;
        float4 w4v = make_float4(0.f, 0.f, 0.f, 0.f);
        if (j < deg) {
            int s = p.ssrc[beg + j];
            soff = s << 8;                       // byte offset into 256 B rows
            float4 a = *(const float4*)(p.asn + s * 4);
            w4v.x = __expf(lrelu(a.x + ad4.x));
            w4v.y = __expf(lrelu(a.y + ad4.y));
            w4v.z = __expf(lrelu(a.z + ad4.z));
            w4v.w = __expf(lrelu(a.w + ad4.w));
        }
        st0[lane] = make_int2(soff, __float_as_int(w4v.x));
        st1[lane] = make_int2(soff, __float_as_int(w4v.y));
        st2[lane] = make_int2(soff, __float_as_int(w4v.z));
        st3[lane] = make_int2(soff, __float_as_int(w4v.w));
        int cnt = deg - base0; if (cnt > 64) cnt = 64;

        int i = 0;
        for (; i + 16 <= cnt; i += 16) {
            int2 p0 = pp[i + 0 + half],  p1 = pp[i + 2 + half];
            int2 p2 = pp[i + 4 + half],  p3 = pp[i + 6 + half];
            int2 p4 = pp[i + 8 + half],  p5 = pp[i + 10 + half];
            int2 p6 = pp[i + 12 + half], p7 = pp[i + 14 + half];
            uint2 u0 = *(const uint2*)(hbase + (unsigned)p0.x);
            uint2 u1 = *(const uint2*)(hbase + (unsigned)p1.x);
            uint2 u2 = *(const uint2*)(hbase + (unsigned)p2.x);
            uint2 u3 = *(const uint2*)(hbase + (unsigned)p3.x);
            uint2 u4 = *(const uint2*)(hbase + (unsigned)p4.x);
            uint2 u5 = *(const uint2*)(hbase + (unsigned)p5.x);
            uint2 u6 = *(const uint2*)(hbase + (unsigned)p6.x);
            uint2 u7 = *(const uint2*)(hbase + (unsigned)p7.x);
            float w0 = __int_as_float(p0.y), w1 = __int_as_float(p1.y);
            float w2 = __int_as_float(p2.y), w3 = __int_as_float(p3.y);
            float w4 = __int_as_float(p4.y), w5 = __int_as_float(p5.y);
            float w6 = __int_as_float(p6.y), w7 = __int_as_float(p7.y);
            denl += w0 + w1 + w2 + w3 + w4 + w5 + w6 + w7;
            a0 += w0 * bflo(u0.x); a1 += w0 * bfhi(u0.x); a2 += w0 * bflo(u0.y); a3 += w0 * bfhi(u0.y);
            a0 += w1 * bflo(u1.x); a1 += w1 * bfhi(u1.x); a2 += w1 * bflo(u1.y); a3 += w1 * bfhi(u1.y);
            a0 += w2 * bflo(u2.x); a1 += w2 * bfhi(u2.x); a2 += w2 * bflo(u2.y); a3 += w2 * bfhi(u2.y);
            a0 += w3 * bflo(u3.x); a1 += w3 * bfhi(u3.x); a2 += w3 * bflo(u3.y); a3 += w3 * bfhi(u3.y);
            a0 += w4 * bflo(u4.x); a1 += w4 * bfhi(u4.x); a2 += w4 * bflo(u4.y); a3 += w4 * bfhi(u4.y);
            a0 += w5 * bflo(u5.x); a1 += w5 * bfhi(u5.x); a2 += w5 * bflo(u5.y); a3 += w5 * bfhi(u5.y);
            a0 += w6 * bflo(u6.x); a1 += w6 * bfhi(u6.x); a2 += w6 * bflo(u6.y); a3 += w6 * bfhi(u6.y);
            a0 += w7 * bflo(u7.x); a1 += w7 * bfhi(u7.x); a2 += w7 * bflo(u7.y); a3 += w7 * bfhi(u7.y);
        }
        for (; i < cnt; i += 4) {                // 4-edge tail; max slot read <= 63
            int2 p0 = pp[i + half], p1 = pp[i + 2 + half];
            uint2 u0 = *(const uint2*)(hbase + (unsigned)p0.x);
            uint2 u1 = *(const uint2*)(hbase + (unsigned)p1.x);
            float w0 = __int_as_float(p0.y), w1 = __int_as_float(p1.y);
            denl += w0 + w1;
            a0 += w0 * bflo(u0.x); a1 += w0 * bfhi(u0.x); a2 += w0 * bflo(u0.y); a3 += w0 * bfhi(u0.y);
            a0 += w1 * bflo(u1.x); a1 += w1 * bfhi(u1.x); a2 += w1 * bflo(u1.y); a3 += w1 * bfhi(u1.y);
        }
    }
    a0 += __shfl_xor(a0, 32); a1 += __shfl_xor(a1, 32);
    a2 += __shfl_xor(a2, 32); a3 += __shfl_xor(a3, 32);
    denl += __shfl_xor(denl, 32);
    if (half == 0) {
        float inv = 1.f / (denl + 1e-16f);
        int c0 = cl * 4;
        float4 bi = *(const float4*)(bias + c0);
        float4 gm = *(const float4*)(gamma + c0);
        float4 bt = *(const float4*)(beta + c0);
        float4 rm = *(const float4*)(rmean + c0);
        float4 rv = *(const float4*)(rvar + c0);
        float o0 = a0 * inv + bi.x, o1 = a1 * inv + bi.y;
        float o2 = a2 * inv + bi.z, o3 = a3 * inv + bi.w;
        o0 = (o0 - rm.x) * rsqrtf(rv.x + EPS_BN) * gm.x + bt.x;
        o1 = (o1 - rm.y) * rsqrtf(rv.y + EPS_BN) * gm.y + bt.y;
        o2 = (o2 - rm.z) * rsqrtf(rv.z + EPS_BN) * gm.z + bt.z;
        o3 = (o3 - rm.w) * rsqrtf(rv.w + EPS_BN) * gm.w + bt.w;
        o0 = (o0 > 0.f) ? o0 : expm1f(o0);
        o1 = (o1 > 0.f) ? o1 : expm1f(o1);
        o2 = (o2 > 0.f) ? o2 : expm1f(o2);
        o3 = (o3 > 0.f) ? o3 : expm1f(o3);
        uint2 ob;
        ob.x = f2bf(o0) | (f2bf(o1) << 16);
        ob.y = f2bf(o2) | (f2bf(o3) << 16);
        *(uint2*)(p.Xb + (size_t)node * 128 + c0) = ob;
    }
}

// =================== layer 2: GEMM(128->8) + attn coeffs ===================

__global__ __launch_bounds__(256) void k_gemm2(GatParams p) {
    __shared__ float sW[128 * 8];
    __shared__ float sas[8], sad[8];
    int tid = threadIdx.x;
    for (int i = tid; i < 1024; i += 256) sW[i] = p.W2[i];
    if (tid < 8) { sas[tid] = p.as2[tid]; sad[tid] = p.ad2[tid]; }
    __syncthreads();
    int node = blockIdx.x * 256 + tid;
    if (node >= N_NODES) return;
    const uint4* xr = (const uint4*)(p.Xb + (size_t)node * 128);
    float acc[8];
    #pragma unroll
    for (int c = 0; c < 8; c++) acc[c] = 0.f;
    for (int k8 = 0; k8 < 16; k8++) {
        uint4 uu = xr[k8];
        float f[8] = { bflo(uu.x), bfhi(uu.x), bflo(uu.y), bfhi(uu.y),
                       bflo(uu.z), bfhi(uu.z), bflo(uu.w), bfhi(uu.w) };
        int kb = k8 * 8;
        #pragma unroll
        for (int q = 0; q < 8; q++)
            #pragma unroll
            for (int c = 0; c < 8; c++)
                acc[c] += f[q] * sW[(kb + q) * 8 + c];
    }
    float ps = 0.f, pd = 0.f;
    #pragma unroll
    for (int c = 0; c < 8; c++) {
        p.h2[(size_t)node * 8 + c] = acc[c];
        ps += acc[c] * sas[c];
        pd += acc[c] * sad[c];
    }
    p.asn[node] = ps;
    p.adn[node] = pd;
}

// =================== layer 2 aggregation + bias + log_softmax ===================

__global__ __launch_bounds__(256) void k_agg2(GatParams p) {
    __shared__ int2 sP[4 * 64];
    int tid = threadIdx.x;
    int wv = tid >> 6, lane = tid & 63;
    int g = lane >> 3, c = lane & 7;
    int node = blockIdx.x * 4 + wv;
    int beg = p.offs[node], end = p.offs[node + 1];
    int deg = end - beg;
    float adv = p.adn[node];
    float den = 0.f, acc = 0.f;
    int2* ws = sP + wv * 64;
    for (int base = 0; base < deg; base += 64) {
        int j = base + lane;
        int s = 0; float w = 0.f;
        if (j < deg) {
            s = p.ssrc[beg + j];
            w = __expf(lrelu(p.asn[s] + adv));
            den += w;
        }
        ws[lane] = make_int2(s, __float_as_int(w));
        int cnt = deg - base; if (cnt > 64) cnt = 64;
        int i = 0;
        for (; i + 16 <= cnt; i += 16) {
            int2 p0 = ws[i + g];
            int2 p1 = ws[i + 8 + g];
            acc += __int_as_float(p0.y) * p.h2[(((unsigned)p0.x) << 3) + c];
            acc += __int_as_float(p1.y) * p.h2[(((unsigned)p1.x) << 3) + c];
        }
        for (; i < cnt; i += 8) {                // 8-edge tail; max slot <= 63
            int2 p0 = ws[i + g];
            acc += __int_as_float(p0.y) * p.h2[(((unsigned)p0.x) << 3) + c];
        }
    }
    acc += __shfl_xor(acc, 8); acc += __shfl_xor(acc, 16); acc += __shfl_xor(acc, 32);
    #pragma unroll
    for (int off = 32; off; off >>= 1) den += __shfl_xor(den, off);
    float o = acc / (den + 1e-16f) + p.b2[c];
    float mx = o;
    mx = fmaxf(mx, __shfl_xor(mx, 1));
    mx = fmaxf(mx, __shfl_xor(mx, 2));
    mx = fmaxf(mx, __shfl_xor(mx, 4));
    float ex = __expf(o - mx);
    float sm = ex;
    sm += __shfl_xor(sm, 1); sm += __shfl_xor(sm, 2); sm += __shfl_xor(sm, 4);
    if (g == 0) p.out[(size_t)node * 8 + c] = o - mx - logf(sm);
}

// =================== launch ===================

extern "C" void kernel_launch(void* const* d_in, const int* in_sizes, int n_in,
                              void* d_out, int out_size, void* d_ws, size_t ws_size,
                              hipStream_t stream) {
    GatParams prm;
    prm.ei  = (const int*)d_in[1];
    prm.x   = (const float*)d_in[0];
    prm.W0  = (const float*)d_in[2];
    prm.as0 = (const float*)d_in[3];  prm.ad0 = (const float*)d_in[4];
    prm.b0  = (const float*)d_in[5];  prm.g0  = (const float*)d_in[6];
    prm.bb0 = (const float*)d_in[7];  prm.rm0 = (const float*)d_in[8];
    prm.rv0 = (const float*)d_in[9];
    prm.W1  = (const float*)d_in[10];
    prm.as1 = (const float*)d_in[11]; prm.ad1 = (const float*)d_in[12];
    prm.b1  = (const float*)d_in[13]; prm.g1  = (const float*)d_in[14];
    prm.bb1 = (const float*)d_in[15]; prm.rm1 = (const float*)d_in[16];
    prm.rv1 = (const float*)d_in[17];
    prm.W2  = (const float*)d_in[18];
    prm.as2 = (const float*)d_in[19]; prm.ad2 = (const float*)d_in[20];
    prm.b2  = (const float*)d_in[21];
    prm.out = (float*)d_out;

    char* w = (char*)d_ws;
    size_t off = 0;
    auto carve = [&](size_t bytes) {
        void* p = w + off;
        off += (bytes + 255) & ~(size_t)255;
        return p;
    };
    prm.xb    = (unsigned short*)carve((size_t)N_NODES * 128 * 2);
    prm.Hb    = (unsigned short*)carve((size_t)N_NODES * 128 * 2);
    prm.Xb    = (unsigned short*)carve((size_t)N_NODES * 128 * 2);
    prm.W0p   = (unsigned short*)carve(16384 * 2);
    prm.W1p   = (unsigned short*)carve(16384 * 2);
    prm.offs  = (int*)carve((size_t)(N_NODES + 1) * 4);
    prm.boffs = (int*)carve((size_t)(NBUCK + 1) * 4);
    prm.bcur  = (int*)carve((size_t)NBUCK * 4);
    prm.ssrc  = (int*)carve((size_t)ET * 4);
    prm.hists = (int*)carve((size_t)PB * NBUCK * 4);
    prm.pairs = (int2*)carve((size_t)ET * 8);
    prm.asn   = (float*)carve((size_t)N_NODES * 4 * 4);
    prm.adn   = (float*)carve((size_t)N_NODES * 4 * 4);
    prm.h2    = (float*)carve((size_t)N_NODES * 8 * 4);
    (void)ws_size; (void)in_sizes; (void)n_in; (void)out_size;

    k_prep<<<PREP_U, 256, 0, stream>>>(prm);
    k_scan<<<1, 256, 0, stream>>>(prm);
    k_partition<<<PB, 256, 0, stream>>>(prm);
    k_group<<<NBUCK, 256, 0, stream>>>(prm);
    k_gemm<<<GB, 256, 0, stream>>>(prm, 0);
    k_agg<<<AGG_U, 256, 0, stream>>>(prm, 0);
    k_gemm<<<GB, 256, 0, stream>>>(prm, 1);
    k_agg<<<AGG_U, 256, 0, stream>>>(prm, 1);
    k_gemm2<<<G2B, 256, 0, stream>>>(prm);
    k_agg2<<<AGG_U, 256, 0, stream>>>(prm);
}

// Round 13
// 290.018 us; speedup vs baseline: 1.1309x; 1.0052x over previous
//
#include <hip/hip_runtime.h>
#include <math.h>

#define N_NODES 50000
#define N_EDGES 800000
#define ET (N_EDGES + N_NODES)   // with self-loops
#define NEG 0.2f
#define EPS_BN 1e-5f

#define BSH 8                                   // 256 nodes per bucket
#define NBUCK ((N_NODES + 255) >> BSH)          // 196
#define EPB 4096                                // edges per partition block
#define PB ((ET + EPB - 1) / EPB)               // 208
#define CAST_B 3125                             // 50000*128/8/256
#define PACK_B 64                               // 16384/256
#define GB ((N_NODES + 63) / 64)                // 782 gemm tiles
#define AGG_U 12500                             // aggregate units (4 nodes each)
#define G2B ((N_NODES + 255) / 256)             // 196
#define PREP_U (PB + CAST_B + 2 * PACK_B)       // 3461

typedef __attribute__((ext_vector_type(8))) short short8;
typedef __attribute__((ext_vector_type(4))) float f32x4;

__device__ __forceinline__ float lrelu(float e) { return e > 0.f ? e : NEG * e; }
__device__ __forceinline__ float bflo(unsigned u) { return __uint_as_float(u << 16); }
__device__ __forceinline__ float bfhi(unsigned u) { return __uint_as_float(u & 0xffff0000u); }
__device__ __forceinline__ unsigned f2bf(float f) {           // RNE round to bf16 bits
    unsigned b = __float_as_uint(f);
    return (b + 0x7fffu + ((b >> 16) & 1u)) >> 16;
}

struct GatParams {
    const int* ei;
    const float* x;
    const float *W0, *as0, *ad0, *b0, *g0, *bb0, *rm0, *rv0;
    const float *W1, *as1, *ad1, *b1, *g1, *bb1, *rm1, *rv1;
    const float *W2, *as2, *ad2, *b2;
    float* out;
    unsigned short *xb, *Hb, *Xb, *W0p, *W1p;
    int *offs, *ssrc, *hists;
    int2* pairs;
    float *asn, *adn, *h2;
};

// =================== prep: per-unit bucket hist + x cast + W pack ===================

__global__ __launch_bounds__(256) void k_prep(GatParams p) {
    __shared__ unsigned h[NBUCK];
    int u = blockIdx.x, tid = threadIdx.x;
    if (u < PB) {
        for (int i = tid; i < NBUCK; i += 256) h[i] = 0;
        __syncthreads();
        int e0 = u * EPB;
        #pragma unroll
        for (int k = 0; k < EPB / 256; k++) {
            int e = e0 + k * 256 + tid;
            if (e < ET) {
                int d = (e < N_EDGES) ? p.ei[N_EDGES + e] : (e - N_EDGES);
                atomicAdd(&h[d >> BSH], 1u);
            }
        }
        __syncthreads();
        for (int i = tid; i < NBUCK; i += 256)
            p.hists[u * NBUCK + i] = (int)h[i];
    } else if (u < PB + CAST_B) {
        int i = (u - PB) * 256 + tid;
        const float4* px = (const float4*)p.x + (size_t)i * 2;
        float4 a = px[0], c = px[1];
        uint4 o;
        o.x = f2bf(a.x) | (f2bf(a.y) << 16);
        o.y = f2bf(a.z) | (f2bf(a.w) << 16);
        o.z = f2bf(c.x) | (f2bf(c.y) << 16);
        o.w = f2bf(c.z) | (f2bf(c.w) << 16);
        ((uint4*)p.xb)[i] = o;
    } else {
        int pb = u - PB - CAST_B;
        const float* W = (pb < PACK_B) ? p.W0 : p.W1;
        unsigned short* Wp = (pb < PACK_B) ? p.W0p : p.W1p;
        int o = (pb & (PACK_B - 1)) * 256 + tid;
        int j = o & 7, lane = (o >> 3) & 63, kc = (o >> 9) & 3, t = o >> 11;
        int k = kc * 32 + ((lane >> 4) << 3) + j;
        int n = t * 16 + (lane & 15);
        Wp[o] = (unsigned short)f2bf(W[k * 128 + n]);
    }
}

// =================== partition: deterministic, atomic-free placement ===================
// Each block u derives its absolute write base per bucket from hists (no global atomics,
// no scan kernel): base[b] = bucketScan(b) + sum_{v<u} hists[v][b]. Single edge pass.

__global__ __launch_bounds__(256) void k_partition(GatParams p) {
    __shared__ int s[256];
    __shared__ int lcur[NBUCK];
    int u = blockIdx.x, tid = threadIdx.x;

    int tot = 0, pre = 0;
    if (tid < NBUCK) {
        const int* hp = p.hists + tid;
        for (int v = 0; v < PB; v++) {
            int hh = hp[v * NBUCK];
            tot += hh;
            if (v < u) pre += hh;
        }
    }
    s[tid] = tot;
    __syncthreads();
    for (int off = 1; off < 256; off <<= 1) {
        int x = (tid >= off) ? s[tid - off] : 0;
        __syncthreads();
        s[tid] += x;
        __syncthreads();
    }
    if (tid < NBUCK) lcur[tid] = (s[tid] - tot) + pre;   // bucket excl-scan + unit prefix
    __syncthreads();

    int e0 = u * EPB;
    #pragma unroll
    for (int k = 0; k < EPB / 256; k++) {
        int e = e0 + k * 256 + tid;
        if (e < ET) {
            int sv, d;
            if (e < N_EDGES) { sv = p.ei[e]; d = p.ei[N_EDGES + e]; }
            else             { sv = d = e - N_EDGES; }
            int pos = atomicAdd(&lcur[d >> BSH], 1);
            p.pairs[pos] = make_int2(sv, d);
        }
    }
}

// =================== group: per-bucket node offsets + regroup ===================

__global__ __launch_bounds__(256) void k_group(GatParams p) {
    __shared__ int s[256];
    __shared__ int cnt[256];
    __shared__ int pfx[256];
    __shared__ int sBase[2];
    int u = blockIdx.x, tid = threadIdx.x;

    // recompute boffs[u], boffs[u+1] from hists
    int tot = 0;
    if (tid < NBUCK) {
        const int* hp = p.hists + tid;
        for (int v = 0; v < PB; v++) tot += hp[v * NBUCK];
    }
    s[tid] = tot;
    __syncthreads();
    for (int off = 1; off < 256; off <<= 1) {
        int x = (tid >= off) ? s[tid - off] : 0;
        __syncthreads();
        s[tid] += x;
        __syncthreads();
    }
    if (tid == u) { sBase[0] = s[tid] - tot; sBase[1] = s[tid]; }
    __syncthreads();
    int base = sBase[0], end = sBase[1];

    int n0 = u << BSH;
    cnt[tid] = 0;
    __syncthreads();
    for (int i = base + tid; i < end; i += 256)
        atomicAdd(&cnt[p.pairs[i].y & 255], 1);
    __syncthreads();
    int v = cnt[tid];
    pfx[tid] = v;
    __syncthreads();
    for (int off = 1; off < 256; off <<= 1) {
        int x = (tid >= off) ? pfx[tid - off] : 0;
        __syncthreads();
        pfx[tid] += x;
        __syncthreads();
    }
    int excl = pfx[tid] - v;
    if (n0 + tid < N_NODES) p.offs[n0 + tid] = base + excl;
    if (u == 0 && tid == 0) p.offs[N_NODES] = ET;
    cnt[tid] = excl;
    __syncthreads();
    for (int i = base + tid; i < end; i += 256) {
        int2 pr = p.pairs[i];
        int pos = atomicAdd(&cnt[pr.y & 255], 1);
        p.ssrc[base + pos] = pr.x;
    }
}

// =================== MFMA GEMM + bf16 h-store + attn coeffs ===================

__global__ __launch_bounds__(256) void k_gemm(GatParams p, int layer) {
    __shared__ float tiles[64 * 132];
    const unsigned short* Ab = (layer == 0) ? p.xb : p.Xb;
    const unsigned short* Wp = (layer == 0) ? p.W0p : p.W1p;
    const float* att_s = (layer == 0) ? p.as0 : p.as1;
    const float* att_d = (layer == 0) ? p.ad0 : p.ad1;
    int tid = threadIdx.x;
    int wv = tid >> 6, lane = tid & 63;
    int base = blockIdx.x * 64;
    int mrow = base + wv * 16 + (lane & 15);
    if (mrow >= N_NODES) mrow = N_NODES - 1;
    int koff = (lane >> 4) * 8;

    f32x4 acc[8];
    #pragma unroll
    for (int t = 0; t < 8; t++) acc[t] = (f32x4){0.f, 0.f, 0.f, 0.f};
    #pragma unroll
    for (int kc = 0; kc < 4; kc++) {
        short8 a = *(const short8*)(Ab + (size_t)mrow * 128 + kc * 32 + koff);
        #pragma unroll
        for (int t = 0; t < 8; t++) {
            short8 b = *(const short8*)(Wp + (((t * 4 + kc) * 64 + lane) << 3));
            acc[t] = __builtin_amdgcn_mfma_f32_16x16x32_bf16(a, b, acc[t], 0, 0, 0);
        }
    }
    int rbase = wv * 16 + (lane >> 4) * 4;
    int col = lane & 15;
    #pragma unroll
    for (int t = 0; t < 8; t++)
        #pragma unroll
        for (int r = 0; r < 4; r++)
            tiles[(rbase + r) * 132 + t * 16 + col] = acc[t][r];
    __syncthreads();

    #pragma unroll
    for (int it = 0; it < 4; it++) {
        int uu = tid + it * 256;
        int rl = uu >> 4, cg4 = uu & 15;
        int row = base + rl;
        if (row < N_NODES) {
            const float* pt = tiles + rl * 132 + cg4 * 8;
            float4 v0 = *(const float4*)(pt);
            float4 v1 = *(const float4*)(pt + 4);
            uint4 o;
            o.x = f2bf(v0.x) | (f2bf(v0.y) << 16);
            o.y = f2bf(v0.z) | (f2bf(v0.w) << 16);
            o.z = f2bf(v1.x) | (f2bf(v1.y) << 16);
            o.w = f2bf(v1.z) | (f2bf(v1.w) << 16);
            *(uint4*)(p.Hb + (size_t)row * 128 + cg4 * 8) = o;
        }
    }
    {
        int rl = tid >> 2, hd = tid & 3;
        int row = base + rl;
        if (row < N_NODES) {
            const float* hrow = tiles + rl * 132 + hd * 32;
            const float* as = att_s + hd * 32;
            const float* ad = att_d + hd * 32;
            float ps = 0.f, pd = 0.f;
            #pragma unroll
            for (int i = 0; i < 8; i++) {
                float4 hv = *(const float4*)(hrow + i * 4);
                float4 sv = *(const float4*)(as + i * 4);
                float4 dv = *(const float4*)(ad + i * 4);
                ps += hv.x * sv.x + hv.y * sv.y + hv.z * sv.z + hv.w * sv.w;
                pd += hv.x * dv.x + hv.y * dv.y + hv.z * dv.z + hv.w * dv.w;
            }
            p.asn[row * 4 + hd] = ps;
            p.adn[row * 4 + hd] = pd;
        }
    }
}

// =================== aggregation + bias + BN + ELU ===================
// Phase C: lane owns 4 channels (uint2); half-wave 0 even edges, half-wave 1 odd.
// 16-edge unrolled main loop + 4-edge tail (slots <= 63 always written by sweep).

__global__ __launch_bounds__(256) void k_agg(GatParams p, int layer) {
    __shared__ int2 sP[4 * 4 * 72];              // [wave][head][72]
    const float* bias  = (layer == 0) ? p.b0  : p.b1;
    const float* gamma = (layer == 0) ? p.g0  : p.g1;
    const float* beta  = (layer == 0) ? p.bb0 : p.bb1;
    const float* rmean = (layer == 0) ? p.rm0 : p.rm1;
    const float* rvar  = (layer == 0) ? p.rv0 : p.rv1;
    int tid = threadIdx.x;
    int wv = tid >> 6, lane = tid & 63;
    int half = lane >> 5, cl = lane & 31, hsel = cl >> 3;
    const char* hbase = (const char*)p.Hb + cl * 8;
    int2* st0 = sP + (wv * 4 + 0) * 72;
    int2* st1 = sP + (wv * 4 + 1) * 72;
    int2* st2 = sP + (wv * 4 + 2) * 72;
    int2* st3 = sP + (wv * 4 + 3) * 72;
    const int2* pp = sP + (wv * 4 + hsel) * 72;

    int node = blockIdx.x * 4 + wv;
    int beg = p.offs[node], deg = p.offs[node + 1] - beg;
    float4 ad4 = *(const float4*)(p.adn + node * 4);
    float a0 = 0.f, a1 = 0.f, a2 = 0.f, a3 = 0.f, denl = 0.f;

    for (int base0 = 0; base0 < deg; base0 += 64) {
        int j = base0 + lane;
        int soff = 0;
        float4 w4v = make_float4(0.f, 0.f, 0.f, 0.f);
        if (j < deg) {
            int s = p.ssrc[beg + j];
            soff = s << 8;                       // byte offset into 256 B rows
            float4 a = *(const float4*)(p.asn + s * 4);
            w4v.x = __expf(lrelu(a.x + ad4.x));
            w4v.y = __expf(lrelu(a.y + ad4.y));
            w4v.z = __expf(lrelu(a.z + ad4.z));
            w4v.w = __expf(lrelu(a.w + ad4.w));
        }
        st0[lane] = make_int2(soff, __float_as_int(w4v.x));
        st1[lane] = make_int2(soff, __float_as_int(w4v.y));
        st2[lane] = make_int2(soff, __float_as_int(w4v.z));
        st3[lane] = make_int2(soff, __float_as_int(w4v.w));
        int cnt = deg - base0; if (cnt > 64) cnt = 64;

        int i = 0;
        for (; i + 16 <= cnt; i += 16) {
            int2 p0 = pp[i + 0 + half],  p1 = pp[i + 2 + half];
            int2 p2 = pp[i + 4 + half],  p3 = pp[i + 6 + half];
            int2 p4 = pp[i + 8 + half],  p5 = pp[i + 10 + half];
            int2 p6 = pp[i + 12 + half], p7 = pp[i + 14 + half];
            uint2 u0 = *(const uint2*)(hbase + (unsigned)p0.x);
            uint2 u1 = *(const uint2*)(hbase + (unsigned)p1.x);
            uint2 u2 = *(const uint2*)(hbase + (unsigned)p2.x);
            uint2 u3 = *(const uint2*)(hbase + (unsigned)p3.x);
            uint2 u4 = *(const uint2*)(hbase + (unsigned)p4.x);
            uint2 u5 = *(const uint2*)(hbase + (unsigned)p5.x);
            uint2 u6 = *(const uint2*)(hbase + (unsigned)p6.x);
            uint2 u7 = *(const uint2*)(hbase + (unsigned)p7.x);
            float w0 = __int_as_float(p0.y), w1 = __int_as_float(p1.y);
            float w2 = __int_as_float(p2.y), w3 = __int_as_float(p3.y);
            float w4 = __int_as_float(p4.y), w5 = __int_as_float(p5.y);
            float w6 = __int_as_float(p6.y), w7 = __int_as_float(p7.y);
            denl += w0 + w1 + w2 + w3 + w4 + w5 + w6 + w7;
            a0 += w0 * bflo(u0.x); a1 += w0 * bfhi(u0.x); a2 += w0 * bflo(u0.y); a3 += w0 * bfhi(u0.y);
            a0 += w1 * bflo(u1.x); a1 += w1 * bfhi(u1.x); a2 += w1 * bflo(u1.y); a3 += w1 * bfhi(u1.y);
            a0 += w2 * bflo(u2.x); a1 += w2 * bfhi(u2.x); a2 += w2 * bflo(u2.y); a3 += w2 * bfhi(u2.y);
            a0 += w3 * bflo(u3.x); a1 += w3 * bfhi(u3.x); a2 += w3 * bflo(u3.y); a3 += w3 * bfhi(u3.y);
            a0 += w4 * bflo(u4.x); a1 += w4 * bfhi(u4.x); a2 += w4 * bflo(u4.y); a3 += w4 * bfhi(u4.y);
            a0 += w5 * bflo(u5.x); a1 += w5 * bfhi(u5.x); a2 += w5 * bflo(u5.y); a3 += w5 * bfhi(u5.y);
            a0 += w6 * bflo(u6.x); a1 += w6 * bfhi(u6.x); a2 += w6 * bflo(u6.y); a3 += w6 * bfhi(u6.y);
            a0 += w7 * bflo(u7.x); a1 += w7 * bfhi(u7.x); a2 += w7 * bflo(u7.y); a3 += w7 * bfhi(u7.y);
        }
        for (; i < cnt; i += 4) {                // 4-edge tail; max slot read <= 63
            int2 p0 = pp[i + half], p1 = pp[i + 2 + half];
            uint2 u0 = *(const uint2*)(hbase + (unsigned)p0.x);
            uint2 u1 = *(const uint2*)(hbase + (unsigned)p1.x);
            float w0 = __int_as_float(p0.y), w1 = __int_as_float(p1.y);
            denl += w0 + w1;
            a0 += w0 * bflo(u0.x); a1 += w0 * bfhi(u0.x); a2 += w0 * bflo(u0.y); a3 += w0 * bfhi(u0.y);
            a0 += w1 * bflo(u1.x); a1 += w1 * bfhi(u1.x); a2 += w1 * bflo(u1.y); a3 += w1 * bfhi(u1.y);
        }
    }
    a0 += __shfl_xor(a0, 32); a1 += __shfl_xor(a1, 32);
    a2 += __shfl_xor(a2, 32); a3 += __shfl_xor(a3, 32);
    denl += __shfl_xor(denl, 32);
    if (half == 0) {
        float inv = 1.f / (denl + 1e-16f);
        int c0 = cl * 4;
        float4 bi = *(const float4*)(bias + c0);
        float4 gm = *(const float4*)(gamma + c0);
        float4 bt = *(const float4*)(beta + c0);
        float4 rm = *(const float4*)(rmean + c0);
        float4 rv = *(const float4*)(rvar + c0);
        float o0 = a0 * inv + bi.x, o1 = a1 * inv + bi.y;
        float o2 = a2 * inv + bi.z, o3 = a3 * inv + bi.w;
        o0 = (o0 - rm.x) * rsqrtf(rv.x + EPS_BN) * gm.x + bt.x;
        o1 = (o1 - rm.y) * rsqrtf(rv.y + EPS_BN) * gm.y + bt.y;
        o2 = (o2 - rm.z) * rsqrtf(rv.z + EPS_BN) * gm.z + bt.z;
        o3 = (o3 - rm.w) * rsqrtf(rv.w + EPS_BN) * gm.w + bt.w;
        o0 = (o0 > 0.f) ? o0 : expm1f(o0);
        o1 = (o1 > 0.f) ? o1 : expm1f(o1);
        o2 = (o2 > 0.f) ? o2 : expm1f(o2);
        o3 = (o3 > 0.f) ? o3 : expm1f(o3);
        uint2 ob;
        ob.x = f2bf(o0) | (f2bf(o1) << 16);
        ob.y = f2bf(o2) | (f2bf(o3) << 16);
        *(uint2*)(p.Xb + (size_t)node * 128 + c0) = ob;
    }
}

// =================== layer 2: GEMM(128->8) + attn coeffs ===================

__global__ __launch_bounds__(256) void k_gemm2(GatParams p) {
    __shared__ float sW[128 * 8];
    __shared__ float sas[8], sad[8];
    int tid = threadIdx.x;
    for (int i = tid; i < 1024; i += 256) sW[i] = p.W2[i];
    if (tid < 8) { sas[tid] = p.as2[tid]; sad[tid] = p.ad2[tid]; }
    __syncthreads();
    int node = blockIdx.x * 256 + tid;
    if (node >= N_NODES) return;
    const uint4* xr = (const uint4*)(p.Xb + (size_t)node * 128);
    float acc[8];
    #pragma unroll
    for (int c = 0; c < 8; c++) acc[c] = 0.f;
    for (int k8 = 0; k8 < 16; k8++) {
        uint4 uu = xr[k8];
        float f[8] = { bflo(uu.x), bfhi(uu.x), bflo(uu.y), bfhi(uu.y),
                       bflo(uu.z), bfhi(uu.z), bflo(uu.w), bfhi(uu.w) };
        int kb = k8 * 8;
        #pragma unroll
        for (int q = 0; q < 8; q++)
            #pragma unroll
            for (int c = 0; c < 8; c++)
                acc[c] += f[q] * sW[(kb + q) * 8 + c];
    }
    float ps = 0.f, pd = 0.f;
    #pragma unroll
    for (int c = 0; c < 8; c++) {
        p.h2[(size_t)node * 8 + c] = acc[c];
        ps += acc[c] * sas[c];
        pd += acc[c] * sad[c];
    }
    p.asn[node] = ps;
    p.adn[node] = pd;
}

// =================== layer 2 aggregation + bias + log_softmax ===================

__global__ __launch_bounds__(256) void k_agg2(GatParams p) {
    __shared__ int2 sP[4 * 64];
    int tid = threadIdx.x;
    int wv = tid >> 6, lane = tid & 63;
    int g = lane >> 3, c = lane & 7;
    int node = blockIdx.x * 4 + wv;
    int beg = p.offs[node], end = p.offs[node + 1];
    int deg = end - beg;
    float adv = p.adn[node];
    float den = 0.f, acc = 0.f;
    int2* ws = sP + wv * 64;
    for (int base = 0; base < deg; base += 64) {
        int j = base + lane;
        int s = 0; float w = 0.f;
        if (j < deg) {
            s = p.ssrc[beg + j];
            w = __expf(lrelu(p.asn[s] + adv));
            den += w;
        }
        ws[lane] = make_int2(s, __float_as_int(w));
        int cnt = deg - base; if (cnt > 64) cnt = 64;
        int i = 0;
        for (; i + 16 <= cnt; i += 16) {
            int2 p0 = ws[i + g];
            int2 p1 = ws[i + 8 + g];
            acc += __int_as_float(p0.y) * p.h2[(((unsigned)p0.x) << 3) + c];
            acc += __int_as_float(p1.y) * p.h2[(((unsigned)p1.x) << 3) + c];
        }
        for (; i < cnt; i += 8) {
            int2 p0 = ws[i + g];
            acc += __int_as_float(p0.y) * p.h2[(((unsigned)p0.x) << 3) + c];
        }
    }
    acc += __shfl_xor(acc, 8); acc += __shfl_xor(acc, 16); acc += __shfl_xor(acc, 32);
    #pragma unroll
    for (int off = 32; off; off >>= 1) den += __shfl_xor(den, off);
    float o = acc / (den + 1e-16f) + p.b2[c];
    float mx = o;
    mx = fmaxf(mx, __shfl_xor(mx, 1));
    mx = fmaxf(mx, __shfl_xor(mx, 2));
    mx = fmaxf(mx, __shfl_xor(mx, 4));
    float ex = __expf(o - mx);
    float sm = ex;
    sm += __shfl_xor(sm, 1); sm += __shfl_xor(sm, 2); sm += __shfl_xor(sm, 4);
    if (g == 0) p.out[(size_t)node * 8 + c] = o - mx - logf(sm);
}

// =================== launch ===================

extern "C" void kernel_launch(void* const* d_in, const int* in_sizes, int n_in,
                              void* d_out, int out_size, void* d_ws, size_t ws_size,
                              hipStream_t stream) {
    GatParams prm;
    prm.ei  = (const int*)d_in[1];
    prm.x   = (const float*)d_in[0];
    prm.W0  = (const float*)d_in[2];
    prm.as0 = (const float*)d_in[3];  prm.ad0 = (const float*)d_in[4];
    prm.b0  = (const float*)d_in[5];  prm.g0  = (const float*)d_in[6];
    prm.bb0 = (const float*)d_in[7];  prm.rm0 = (const float*)d_in[8];
    prm.rv0 = (const float*)d_in[9];
    prm.W1  = (const float*)d_in[10];
    prm.as1 = (const float*)d_in[11]; prm.ad1 = (const float*)d_in[12];
    prm.b1  = (const float*)d_in[13]; prm.g1  = (const float*)d_in[14];
    prm.bb1 = (const float*)d_in[15]; prm.rm1 = (const float*)d_in[16];
    prm.rv1 = (const float*)d_in[17];
    prm.W2  = (const float*)d_in[18];
    prm.as2 = (const float*)d_in[19]; prm.ad2 = (const float*)d_in[20];
    prm.b2  = (const float*)d_in[21];
    prm.out = (float*)d_out;

    char* w = (char*)d_ws;
    size_t off = 0;
    auto carve = [&](size_t bytes) {
        void* p = w + off;
        off += (bytes + 255) & ~(size_t)255;
        return p;
    };
    prm.xb    = (unsigned short*)carve((size_t)N_NODES * 128 * 2);
    prm.Hb    = (unsigned short*)carve((size_t)N_NODES * 128 * 2);
    prm.Xb    = (unsigned short*)carve((size_t)N_NODES * 128 * 2);
    prm.W0p   = (unsigned short*)carve(16384 * 2);
    prm.W1p   = (unsigned short*)carve(16384 * 2);
    prm.offs  = (int*)carve((size_t)(N_NODES + 1) * 4);
    prm.ssrc  = (int*)carve((size_t)ET * 4);
    prm.hists = (int*)carve((size_t)PB * NBUCK * 4);
    prm.pairs = (int2*)carve((size_t)ET * 8);
    prm.asn   = (float*)carve((size_t)N_NODES * 4 * 4);
    prm.adn   = (float*)carve((size_t)N_NODES * 4 * 4);
    prm.h2    = (float*)carve((size_t)N_NODES * 8 * 4);
    (void)ws_size; (void)in_sizes; (void)n_in; (void)out_size;

    k_prep<<<PREP_U, 256, 0, stream>>>(prm);
    k_partition<<<PB, 256, 0, stream>>>(prm);
    k_group<<<NBUCK, 256, 0, stream>>>(prm);
    k_gemm<<<GB, 256, 0, stream>>>(prm, 0);
    k_agg<<<AGG_U, 256, 0, stream>>>(prm, 0);
    k_gemm<<<GB, 256, 0, stream>>>(prm, 1);
    k_agg<<<AGG_U, 256, 0, stream>>>(prm, 1);
    k_gemm2<<<G2B, 256, 0, stream>>>(prm);
    k_agg2<<<AGG_U, 256, 0, stream>>>(prm);
}